// Round 1
// baseline (1630.833 us; speedup 1.0000x reference)
//
#include <hip/hip_runtime.h>

// Problem constants (from reference)
constexpr int Bc = 1;
constexpr int Lc = 16;
constexpr int Cc = 16;
constexpr int Hc = 128;
constexpr int Wc = 256;
constexpr float DECAYc = 0.1f;
constexpr int HWc = Hc * Wc;

// out[t,c,h,w] = sum_{k<=t} w[t,k] * bilinear(img[k,c], g(t,k,h,w))
// g_x = base_x[w] + fx[t,h,w] - fx[k,h,w], wrapped to [-1,1) (x wraps mod W)
// g_y = base_y[h] + fy[t,h,w] - fy[k,h,w], y clamped to [0,H-1]
__global__ __launch_bounds__(256) void gridsample_warp_acc(
    const float* __restrict__ img,       // (L, C, H, W)
    const float* __restrict__ cum_flow,  // (L, 2, H, W)
    const float* __restrict__ mask,      // (L, L)
    const float* __restrict__ decay,     // (L, L)
    float* __restrict__ out)             // (L, C, H, W)
{
    const int w = threadIdx.x;   // 0..255  (== Wc)
    const int h = blockIdx.x;    // 0..127
    const int t = blockIdx.y;    // 0..15

    const int pix = h * Wc + w;

    // base grid (matches reference exactly; all terms are exact powers of two)
    const float base_x = w * (2.0f / Wc) - 1.0f + 1.0f / Wc;
    const float base_y = h * (2.0f / Hc) - 1.0f + 1.0f / Hc;

    const float fxt = cum_flow[(t * 2 + 0) * HWc + pix];
    const float fyt = cum_flow[(t * 2 + 1) * HWc + pix];

    float acc[Cc];
#pragma unroll
    for (int c = 0; c < Cc; ++c) acc[c] = 0.0f;

    for (int k = 0; k <= t; ++k) {
        // weight (mask[t,k] == 1 for k<=t, but read it to stay faithful)
        const float wkt = mask[t * Lc + k] * expf(-DECAYc * decay[t * Lc + k]);

        const float fxk = cum_flow[(k * 2 + 0) * HWc + pix];
        const float fyk = cum_flow[(k * 2 + 1) * HWc + pix];

        float gx = base_x + (fxt - fxk);
        const float gy = base_y + (fyt - fyk);

        // gx = mod(gx + 1, 2) - 1   (Python mod: result in [0,2))
        {
            float m = gx + 1.0f;
            m -= 2.0f * floorf(m * 0.5f);
            gx = m - 1.0f;
        }

        const float ix = (gx + 1.0f) * (Wc * 0.5f) - 0.5f;
        const float iy = (gy + 1.0f) * (Hc * 0.5f) - 0.5f;

        const float x0f = floorf(ix);
        const float y0f = floorf(iy);
        const float wx = ix - x0f;
        const float wy = iy - y0f;

        const int x0 = (int)x0f;             // in [-1, 255]
        const int y0 = (int)y0f;             // roughly [-40, 168]
        const int x0r = x0 & (Wc - 1);       // wrap (handles -1 -> 255)
        const int x1r = (x0 + 1) & (Wc - 1);
        const int y0c = min(max(y0, 0), Hc - 1);
        const int y1c = min(max(y0 + 1, 0), Hc - 1);

        // fold wkt into bilinear weights: 4 muls here, 4 FMAs per channel below
        const float a00 = wkt * (1.0f - wx) * (1.0f - wy);
        const float a01 = wkt * (1.0f - wx) * wy;
        const float a10 = wkt * wx * (1.0f - wy);
        const float a11 = wkt * wx * wy;

        const int o00 = y0c * Wc + x0r;
        const int o01 = y1c * Wc + x0r;
        const int o10 = y0c * Wc + x1r;
        const int o11 = y1c * Wc + x1r;

        const float* __restrict__ ik = img + (size_t)k * Cc * HWc;
#pragma unroll
        for (int c = 0; c < Cc; ++c) {
            const float* __restrict__ p = ik + c * HWc;
            const float va = p[o00];
            const float vb = p[o01];
            const float vc = p[o10];
            const float vd = p[o11];
            acc[c] += va * a00 + vb * a01 + vc * a10 + vd * a11;
        }
    }

    float* __restrict__ op = out + (size_t)t * Cc * HWc + pix;
#pragma unroll
    for (int c = 0; c < Cc; ++c) op[c * HWc] = acc[c];
}

extern "C" void kernel_launch(void* const* d_in, const int* in_sizes, int n_in,
                              void* d_out, int out_size, void* d_ws, size_t ws_size,
                              hipStream_t stream) {
    const float* img      = (const float*)d_in[0];  // (B,L,C,H,W) = 8388608
    const float* cum_flow = (const float*)d_in[1];  // (B,L,2,H,W) = 1048576
    const float* mask     = (const float*)d_in[2];  // (L,L)
    const float* decay    = (const float*)d_in[3];  // (L,L)
    float* out = (float*)d_out;                     // (B,L,C,H,W)

    dim3 grid(Hc, Lc, 1);   // (h, t)
    dim3 block(Wc, 1, 1);   // w
    gridsample_warp_acc<<<grid, block, 0, stream>>>(img, cum_flow, mask, decay, out);
}

// Round 2
// 296.346 us; speedup vs baseline: 5.5031x; 5.5031x over previous
//
#include <hip/hip_runtime.h>

constexpr int Lc = 16;
constexpr int Cc = 16;
constexpr int Hc = 128;
constexpr int Wc = 256;
constexpr float DECAYc = 0.1f;
constexpr int HWc = Hc * Wc;

// ---------------------------------------------------------------------------
// Kernel 1: transpose img (L,C,H,W) -> imgT (L,H,W,C)  [channels-last]
// Each thread: one (k, pix); reads 16 floats strided HW (coalesced across
// lanes per channel), writes one contiguous 64B chunk.
// ---------------------------------------------------------------------------
__global__ __launch_bounds__(256) void transpose_chlast(
    const float* __restrict__ img, float* __restrict__ imgT)
{
    const int pix = blockIdx.x * 256 + threadIdx.x;  // 0..HW-1
    const int k = blockIdx.y;                        // 0..L-1

    const float* __restrict__ src = img + (size_t)k * Cc * HWc + pix;
    float4* __restrict__ dst = (float4*)(imgT + ((size_t)k * HWc + pix) * Cc);

    float v[Cc];
#pragma unroll
    for (int c = 0; c < Cc; ++c) v[c] = src[c * HWc];
#pragma unroll
    for (int q = 0; q < 4; ++q)
        dst[q] = make_float4(v[4 * q + 0], v[4 * q + 1], v[4 * q + 2], v[4 * q + 3]);
}

// ---------------------------------------------------------------------------
// Kernel 2: warp-accumulate from channels-last imgT.
// out[t,c,h,w] = sum_{k<=t} w[t,k] * bilinear(img[k,c], g(t,k,h,w))
// k==t is an exact identity sample (ix==w, iy==h, weight==1): direct add.
// ---------------------------------------------------------------------------
__global__ __launch_bounds__(256) void gridsample_chlast(
    const float* __restrict__ imgT,      // (L, H, W, C)
    const float* __restrict__ cum_flow,  // (L, 2, H, W)
    const float* __restrict__ mask,      // (L, L)
    const float* __restrict__ decay,     // (L, L)
    const float* __restrict__ img,       // (L, C, H, W) original, for k==t
    float* __restrict__ out)             // (L, C, H, W)
{
    const int w = threadIdx.x;   // 0..255
    const int h = blockIdx.x;    // 0..127
    const int t = blockIdx.y;    // 0..15

    const int pix = h * Wc + w;

    const float base_x = w * (2.0f / Wc) - 1.0f + 1.0f / Wc;
    const float base_y = h * (2.0f / Hc) - 1.0f + 1.0f / Hc;

    const float fxt = cum_flow[(t * 2 + 0) * HWc + pix];
    const float fyt = cum_flow[(t * 2 + 1) * HWc + pix];

    float4 acc0 = {0, 0, 0, 0}, acc1 = {0, 0, 0, 0};
    float4 acc2 = {0, 0, 0, 0}, acc3 = {0, 0, 0, 0};

    for (int k = 0; k < t; ++k) {
        const float wkt = mask[t * Lc + k] * __expf(-DECAYc * decay[t * Lc + k]);

        const float fxk = cum_flow[(k * 2 + 0) * HWc + pix];
        const float fyk = cum_flow[(k * 2 + 1) * HWc + pix];

        float gx = base_x + (fxt - fxk);
        const float gy = base_y + (fyt - fyk);

        // gx = mod(gx + 1, 2) - 1  (Python mod semantics)
        {
            float m = gx + 1.0f;
            m -= 2.0f * floorf(m * 0.5f);
            gx = m - 1.0f;
        }

        const float ix = (gx + 1.0f) * (Wc * 0.5f) - 0.5f;
        const float iy = (gy + 1.0f) * (Hc * 0.5f) - 0.5f;

        const float x0f = floorf(ix);
        const float y0f = floorf(iy);
        const float wx = ix - x0f;
        const float wy = iy - y0f;

        const int x0 = (int)x0f;
        const int y0 = (int)y0f;
        const int x0r = x0 & (Wc - 1);
        const int x1r = (x0 + 1) & (Wc - 1);
        const int y0c = min(max(y0, 0), Hc - 1);
        const int y1c = min(max(y0 + 1, 0), Hc - 1);

        const float a00 = wkt * (1.0f - wx) * (1.0f - wy);
        const float a01 = wkt * (1.0f - wx) * wy;
        const float a10 = wkt * wx * (1.0f - wy);
        const float a11 = wkt * wx * wy;

        const float* __restrict__ bk = imgT + (size_t)k * HWc * Cc;
        const float4* __restrict__ p00 = (const float4*)(bk + (y0c * Wc + x0r) * Cc);
        const float4* __restrict__ p10 = (const float4*)(bk + (y0c * Wc + x1r) * Cc);
        const float4* __restrict__ p01 = (const float4*)(bk + (y1c * Wc + x0r) * Cc);
        const float4* __restrict__ p11 = (const float4*)(bk + (y1c * Wc + x1r) * Cc);

#pragma unroll
        for (int q = 0; q < 4; ++q) {
            const float4 v00 = p00[q];
            const float4 v10 = p10[q];
            const float4 v01 = p01[q];
            const float4 v11 = p11[q];
            float4& a = (q == 0) ? acc0 : (q == 1) ? acc1 : (q == 2) ? acc2 : acc3;
            a.x += a00 * v00.x + a10 * v10.x + a01 * v01.x + a11 * v11.x;
            a.y += a00 * v00.y + a10 * v10.y + a01 * v01.y + a11 * v11.y;
            a.z += a00 * v00.z + a10 * v10.z + a01 * v01.z + a11 * v11.z;
            a.w += a00 * v00.w + a10 * v10.w + a01 * v01.w + a11 * v11.w;
        }
    }

    // k == t: exact identity sample, weight 1.0 — coalesced direct add.
    {
        const float* __restrict__ p = img + (size_t)t * Cc * HWc + pix;
        acc0.x += p[0 * HWc];  acc0.y += p[1 * HWc];  acc0.z += p[2 * HWc];  acc0.w += p[3 * HWc];
        acc1.x += p[4 * HWc];  acc1.y += p[5 * HWc];  acc1.z += p[6 * HWc];  acc1.w += p[7 * HWc];
        acc2.x += p[8 * HWc];  acc2.y += p[9 * HWc];  acc2.z += p[10 * HWc]; acc2.w += p[11 * HWc];
        acc3.x += p[12 * HWc]; acc3.y += p[13 * HWc]; acc3.z += p[14 * HWc]; acc3.w += p[15 * HWc];
    }

    float* __restrict__ op = out + (size_t)t * Cc * HWc + pix;
    const float accs[Cc] = {acc0.x, acc0.y, acc0.z, acc0.w,
                            acc1.x, acc1.y, acc1.z, acc1.w,
                            acc2.x, acc2.y, acc2.z, acc2.w,
                            acc3.x, acc3.y, acc3.z, acc3.w};
#pragma unroll
    for (int c = 0; c < Cc; ++c) op[c * HWc] = accs[c];
}

// ---------------------------------------------------------------------------
// Fallback (Round-1 kernel): used only if ws_size is too small for imgT.
// ---------------------------------------------------------------------------
__global__ __launch_bounds__(256) void gridsample_warp_acc(
    const float* __restrict__ img, const float* __restrict__ cum_flow,
    const float* __restrict__ mask, const float* __restrict__ decay,
    float* __restrict__ out)
{
    const int w = threadIdx.x, h = blockIdx.x, t = blockIdx.y;
    const int pix = h * Wc + w;
    const float base_x = w * (2.0f / Wc) - 1.0f + 1.0f / Wc;
    const float base_y = h * (2.0f / Hc) - 1.0f + 1.0f / Hc;
    const float fxt = cum_flow[(t * 2 + 0) * HWc + pix];
    const float fyt = cum_flow[(t * 2 + 1) * HWc + pix];
    float acc[Cc];
#pragma unroll
    for (int c = 0; c < Cc; ++c) acc[c] = 0.0f;
    for (int k = 0; k <= t; ++k) {
        const float wkt = mask[t * Lc + k] * __expf(-DECAYc * decay[t * Lc + k]);
        const float fxk = cum_flow[(k * 2 + 0) * HWc + pix];
        const float fyk = cum_flow[(k * 2 + 1) * HWc + pix];
        float gx = base_x + (fxt - fxk);
        const float gy = base_y + (fyt - fyk);
        float m = gx + 1.0f;
        m -= 2.0f * floorf(m * 0.5f);
        gx = m - 1.0f;
        const float ix = (gx + 1.0f) * (Wc * 0.5f) - 0.5f;
        const float iy = (gy + 1.0f) * (Hc * 0.5f) - 0.5f;
        const float x0f = floorf(ix), y0f = floorf(iy);
        const float wx = ix - x0f, wy = iy - y0f;
        const int x0 = (int)x0f, y0 = (int)y0f;
        const int x0r = x0 & (Wc - 1), x1r = (x0 + 1) & (Wc - 1);
        const int y0c = min(max(y0, 0), Hc - 1), y1c = min(max(y0 + 1, 0), Hc - 1);
        const float a00 = wkt * (1.0f - wx) * (1.0f - wy);
        const float a01 = wkt * (1.0f - wx) * wy;
        const float a10 = wkt * wx * (1.0f - wy);
        const float a11 = wkt * wx * wy;
        const int o00 = y0c * Wc + x0r, o01 = y1c * Wc + x0r;
        const int o10 = y0c * Wc + x1r, o11 = y1c * Wc + x1r;
        const float* __restrict__ ik = img + (size_t)k * Cc * HWc;
#pragma unroll
        for (int c = 0; c < Cc; ++c) {
            const float* __restrict__ p = ik + c * HWc;
            acc[c] += p[o00] * a00 + p[o01] * a01 + p[o10] * a10 + p[o11] * a11;
        }
    }
    float* __restrict__ op = out + (size_t)t * Cc * HWc + pix;
#pragma unroll
    for (int c = 0; c < Cc; ++c) op[c * HWc] = acc[c];
}

extern "C" void kernel_launch(void* const* d_in, const int* in_sizes, int n_in,
                              void* d_out, int out_size, void* d_ws, size_t ws_size,
                              hipStream_t stream) {
    const float* img      = (const float*)d_in[0];
    const float* cum_flow = (const float*)d_in[1];
    const float* mask     = (const float*)d_in[2];
    const float* decay    = (const float*)d_in[3];
    float* out = (float*)d_out;

    const size_t needed = (size_t)Lc * HWc * Cc * sizeof(float);  // 32 MB
    if (ws_size >= needed) {
        float* imgT = (float*)d_ws;
        dim3 tgrid(HWc / 256, Lc, 1);
        transpose_chlast<<<tgrid, 256, 0, stream>>>(img, imgT);
        dim3 grid(Hc, Lc, 1);
        gridsample_chlast<<<grid, Wc, 0, stream>>>(imgT, cum_flow, mask, decay, img, out);
    } else {
        dim3 grid(Hc, Lc, 1);
        gridsample_warp_acc<<<grid, Wc, 0, stream>>>(img, cum_flow, mask, decay, out);
    }
}

// Round 3
// 185.229 us; speedup vs baseline: 8.8044x; 1.5999x over previous
//
#include <hip/hip_runtime.h>

constexpr int Lc = 16;
constexpr int Cc = 16;
constexpr int Hc = 128;
constexpr int Wc = 256;
constexpr float DECAYc = 0.1f;
constexpr int HWc = Hc * Wc;

// ---------------------------------------------------------------------------
// Kernel 1: transpose img (L,C,H,W) -> imgT (L,H,W,C)  [channels-last]
// Lane mapping: lane = 4*wq + q. Thread (wq,q) reads channels 4q..4q+3 of its
// pixel (4 planes x 16-consecutive-words per instr) and writes ONE float4 at
// pix*64B + q*16B -> 4 consecutive lanes form one fully-consumed 64B line.
// ---------------------------------------------------------------------------
__global__ __launch_bounds__(256) void transpose_chlast(
    const float* __restrict__ img, float* __restrict__ imgT)
{
    const int tid = threadIdx.x;
    const int wq = tid >> 2;                         // 0..63 pixel-in-block
    const int q  = tid & 3;                          // quarter
    const int pix = blockIdx.x * 64 + wq;            // 0..HW-1
    const int k = blockIdx.y;                        // 0..L-1

    const float* __restrict__ src = img + (size_t)k * Cc * HWc + pix;
    float4 v;
    v.x = src[(4 * q + 0) * HWc];
    v.y = src[(4 * q + 1) * HWc];
    v.z = src[(4 * q + 2) * HWc];
    v.w = src[(4 * q + 3) * HWc];
    float4* __restrict__ dst = (float4*)(imgT + ((size_t)k * HWc + pix) * Cc);
    dst[q] = v;
}

// ---------------------------------------------------------------------------
// Kernel 2: warp-accumulate, quarter-split lanes.
// lane = 4*wq + q : 4 consecutive lanes cover the 4 float4 quarters of one
// pixel's 64B channels-last line -> each neighbor load instr coalesces to
// 16 full-line requests (minimum possible).
// ---------------------------------------------------------------------------
__global__ __launch_bounds__(256) void gridsample_chlast_q(
    const float* __restrict__ imgT,      // (L, H, W, C)
    const float* __restrict__ cum_flow,  // (L, 2, H, W)
    const float* __restrict__ mask,      // (L, L)
    const float* __restrict__ decay,     // (L, L)
    float* __restrict__ out)             // (L, C, H, W)
{
    const int tid = threadIdx.x;
    const int wq = tid >> 2;             // 0..63: pixel within block
    const int q  = tid & 3;              // 0..3 : channel quarter
    const int bx = blockIdx.x;           // 0..511
    const int h  = bx >> 2;              // 0..127
    const int w  = (bx & 3) * 64 + wq;   // 0..255
    const int t  = blockIdx.y;           // 0..15

    const int pix = h * Wc + w;

    const float base_x = w * (2.0f / Wc) - 1.0f + 1.0f / Wc;
    const float base_y = h * (2.0f / Hc) - 1.0f + 1.0f / Hc;

    const float fxt = cum_flow[(t * 2 + 0) * HWc + pix];
    const float fyt = cum_flow[(t * 2 + 1) * HWc + pix];

    float4 acc = {0.0f, 0.0f, 0.0f, 0.0f};

    for (int k = 0; k < t; ++k) {
        const float wkt = mask[t * Lc + k] * __expf(-DECAYc * decay[t * Lc + k]);

        const float fxk = cum_flow[(k * 2 + 0) * HWc + pix];
        const float fyk = cum_flow[(k * 2 + 1) * HWc + pix];

        float gx = base_x + (fxt - fxk);
        const float gy = base_y + (fyt - fyk);

        // gx = mod(gx + 1, 2) - 1  (Python mod semantics)
        {
            float m = gx + 1.0f;
            m -= 2.0f * floorf(m * 0.5f);
            gx = m - 1.0f;
        }

        const float ix = (gx + 1.0f) * (Wc * 0.5f) - 0.5f;
        const float iy = (gy + 1.0f) * (Hc * 0.5f) - 0.5f;

        const float x0f = floorf(ix);
        const float y0f = floorf(iy);
        const float wx = ix - x0f;
        const float wy = iy - y0f;

        const int x0 = (int)x0f;
        const int y0 = (int)y0f;
        const int x0r = x0 & (Wc - 1);
        const int x1r = (x0 + 1) & (Wc - 1);
        const int y0c = min(max(y0, 0), Hc - 1);
        const int y1c = min(max(y0 + 1, 0), Hc - 1);

        const float a00 = wkt * (1.0f - wx) * (1.0f - wy);
        const float a01 = wkt * (1.0f - wx) * wy;
        const float a10 = wkt * wx * (1.0f - wy);
        const float a11 = wkt * wx * wy;

        const float* __restrict__ bk = imgT + (size_t)k * HWc * Cc;
        const float4 v00 = ((const float4*)(bk + (y0c * Wc + x0r) * Cc))[q];
        const float4 v10 = ((const float4*)(bk + (y0c * Wc + x1r) * Cc))[q];
        const float4 v01 = ((const float4*)(bk + (y1c * Wc + x0r) * Cc))[q];
        const float4 v11 = ((const float4*)(bk + (y1c * Wc + x1r) * Cc))[q];

        acc.x += a00 * v00.x + a10 * v10.x + a01 * v01.x + a11 * v11.x;
        acc.y += a00 * v00.y + a10 * v10.y + a01 * v01.y + a11 * v11.y;
        acc.z += a00 * v00.z + a10 * v10.z + a01 * v01.z + a11 * v11.z;
        acc.w += a00 * v00.w + a10 * v10.w + a01 * v01.w + a11 * v11.w;
    }

    // k == t: exact identity sample, weight 1.0 — coalesced full-line read.
    {
        const float4 idv = ((const float4*)(imgT + ((size_t)t * HWc + pix) * Cc))[q];
        acc.x += idv.x;
        acc.y += idv.y;
        acc.z += idv.z;
        acc.w += idv.w;
    }

    float* __restrict__ op = out + (size_t)t * Cc * HWc + (size_t)(4 * q) * HWc + pix;
    op[0 * HWc] = acc.x;
    op[1 * HWc] = acc.y;
    op[2 * HWc] = acc.z;
    op[3 * HWc] = acc.w;
}

// ---------------------------------------------------------------------------
// Fallback (Round-1 kernel): used only if ws_size is too small for imgT.
// ---------------------------------------------------------------------------
__global__ __launch_bounds__(256) void gridsample_warp_acc(
    const float* __restrict__ img, const float* __restrict__ cum_flow,
    const float* __restrict__ mask, const float* __restrict__ decay,
    float* __restrict__ out)
{
    const int w = threadIdx.x, h = blockIdx.x, t = blockIdx.y;
    const int pix = h * Wc + w;
    const float base_x = w * (2.0f / Wc) - 1.0f + 1.0f / Wc;
    const float base_y = h * (2.0f / Hc) - 1.0f + 1.0f / Hc;
    const float fxt = cum_flow[(t * 2 + 0) * HWc + pix];
    const float fyt = cum_flow[(t * 2 + 1) * HWc + pix];
    float acc[Cc];
#pragma unroll
    for (int c = 0; c < Cc; ++c) acc[c] = 0.0f;
    for (int k = 0; k <= t; ++k) {
        const float wkt = mask[t * Lc + k] * __expf(-DECAYc * decay[t * Lc + k]);
        const float fxk = cum_flow[(k * 2 + 0) * HWc + pix];
        const float fyk = cum_flow[(k * 2 + 1) * HWc + pix];
        float gx = base_x + (fxt - fxk);
        const float gy = base_y + (fyt - fyk);
        float m = gx + 1.0f;
        m -= 2.0f * floorf(m * 0.5f);
        gx = m - 1.0f;
        const float ix = (gx + 1.0f) * (Wc * 0.5f) - 0.5f;
        const float iy = (gy + 1.0f) * (Hc * 0.5f) - 0.5f;
        const float x0f = floorf(ix), y0f = floorf(iy);
        const float wx = ix - x0f, wy = iy - y0f;
        const int x0 = (int)x0f, y0 = (int)y0f;
        const int x0r = x0 & (Wc - 1), x1r = (x0 + 1) & (Wc - 1);
        const int y0c = min(max(y0, 0), Hc - 1), y1c = min(max(y0 + 1, 0), Hc - 1);
        const float a00 = wkt * (1.0f - wx) * (1.0f - wy);
        const float a01 = wkt * (1.0f - wx) * wy;
        const float a10 = wkt * wx * (1.0f - wy);
        const float a11 = wkt * wx * wy;
        const int o00 = y0c * Wc + x0r, o01 = y1c * Wc + x0r;
        const int o10 = y0c * Wc + x1r, o11 = y1c * Wc + x1r;
        const float* __restrict__ ik = img + (size_t)k * Cc * HWc;
#pragma unroll
        for (int c = 0; c < Cc; ++c) {
            const float* __restrict__ p = ik + c * HWc;
            acc[c] += p[o00] * a00 + p[o01] * a01 + p[o10] * a10 + p[o11] * a11;
        }
    }
    float* __restrict__ op = out + (size_t)t * Cc * HWc + pix;
#pragma unroll
    for (int c = 0; c < Cc; ++c) op[c * HWc] = acc[c];
}

extern "C" void kernel_launch(void* const* d_in, const int* in_sizes, int n_in,
                              void* d_out, int out_size, void* d_ws, size_t ws_size,
                              hipStream_t stream) {
    const float* img      = (const float*)d_in[0];
    const float* cum_flow = (const float*)d_in[1];
    const float* mask     = (const float*)d_in[2];
    const float* decay    = (const float*)d_in[3];
    float* out = (float*)d_out;

    const size_t needed = (size_t)Lc * HWc * Cc * sizeof(float);  // 32 MB
    if (ws_size >= needed) {
        float* imgT = (float*)d_ws;
        dim3 tgrid(HWc / 64, Lc, 1);   // 512 x 16, 64 px/block
        transpose_chlast<<<tgrid, 256, 0, stream>>>(img, imgT);
        dim3 grid(Hc * (Wc / 64), Lc, 1);  // 512 x 16
        gridsample_chlast_q<<<grid, 256, 0, stream>>>(imgT, cum_flow, mask, decay, out);
    } else {
        dim3 grid(Hc, Lc, 1);
        gridsample_warp_acc<<<grid, Wc, 0, stream>>>(img, cum_flow, mask, decay, out);
    }
}

// Round 4
// 158.220 us; speedup vs baseline: 10.3074x; 1.1707x over previous
//
#include <hip/hip_runtime.h>

constexpr int Lc = 16;
constexpr int Cc = 16;
constexpr int Hc = 128;
constexpr int Wc = 256;
constexpr float DECAYc = 0.1f;
constexpr int HWc = Hc * Wc;

// ---------------------------------------------------------------------------
// Kernel 1: transpose img (L,C,H,W) -> imgT (L,H,W,C) via LDS tile.
// Block = 256 threads, tile = 256 pixels of one frame k.
// Phase 1: float4 global loads (16 full lines/instr), scatter into padded LDS.
// Phase 2: gather float4 from LDS, float4 global stores (16 full lines/instr).
// LDS pad 17 -> all phases <=2-way bank aliasing (free on CDNA4).
// ---------------------------------------------------------------------------
__global__ __launch_bounds__(256) void transpose_chlast_lds(
    const float* __restrict__ img, float* __restrict__ imgT)
{
    __shared__ float tile[256 * 17];  // [px][17], index px*17 + c
    const int tid = threadIdx.x;
    const int k = blockIdx.y;
    const int px0 = blockIdx.x * 256;

    // Phase 1: c = tid>>4 (plane), g = tid&15 -> float4 of 4 consecutive px
    {
        const int c = tid >> 4;
        const int g = tid & 15;
        const float* __restrict__ src = img + (size_t)k * Cc * HWc + (size_t)c * HWc + px0;
#pragma unroll
        for (int r = 0; r < 4; ++r) {
            const int p4 = 4 * (g + 16 * r);
            const float4 v = *(const float4*)(src + p4);
            tile[(p4 + 0) * 17 + c] = v.x;
            tile[(p4 + 1) * 17 + c] = v.y;
            tile[(p4 + 2) * 17 + c] = v.z;
            tile[(p4 + 3) * 17 + c] = v.w;
        }
    }
    __syncthreads();
    // Phase 2: px = tid>>2 + 64r, q = tid&3 -> one float4 (channels 4q..4q+3)
    {
        const int q = tid & 3;
        const int pb = tid >> 2;
#pragma unroll
        for (int r = 0; r < 4; ++r) {
            const int px = pb + 64 * r;
            float4 o;
            o.x = tile[px * 17 + 4 * q + 0];
            o.y = tile[px * 17 + 4 * q + 1];
            o.z = tile[px * 17 + 4 * q + 2];
            o.w = tile[px * 17 + 4 * q + 3];
            ((float4*)(imgT + ((size_t)k * HWc + px0 + px) * Cc))[q] = o;
        }
    }
}

// ---------------------------------------------------------------------------
// Kernel 2: t-merged warp-accumulate. One block = 64 pixels, ALL 16 t's.
// k outer (dynamic, wave-uniform), t inner (fully unrolled; uniform branches
// keep acc[]/fxs[] statically indexed). Band-swizzle: blockIdx.x & 7 picks the
// 16-row h-band -> per-XCD L2 locality (heuristic round-robin XCD mapping).
// ---------------------------------------------------------------------------
__global__ __launch_bounds__(256) void gridsample_tmerge(
    const float* __restrict__ imgT,      // (L, H, W, C)
    const float* __restrict__ cum_flow,  // (L, 2, H, W)
    const float* __restrict__ mask,      // (L, L)
    const float* __restrict__ decay,     // (L, L)
    float* __restrict__ out)             // (L, C, H, W)
{
    const int tid = threadIdx.x;
    const int wq = tid >> 2;             // 0..63: pixel within block
    const int q  = tid & 3;              // 0..3 : channel quarter
    const int bx = blockIdx.x;           // 0..511
    const int band = bx & 7;             // XCD-aligned 16-row band
    const int sub  = bx >> 3;            // 0..63
    const int h = band * 16 + (sub >> 2);
    const int w = (sub & 3) * 64 + wq;

    const int pix = h * Wc + w;

    const float base_x = w * (2.0f / Wc) - 1.0f + 1.0f / Wc;
    const float base_y = h * (2.0f / Hc) - 1.0f + 1.0f / Hc;

    // Preload per-pixel flow for all frames (statically indexed registers).
    float fxs[Lc], fys[Lc];
#pragma unroll
    for (int t = 0; t < Lc; ++t) {
        fxs[t] = cum_flow[(t * 2 + 0) * HWc + pix];
        fys[t] = cum_flow[(t * 2 + 1) * HWc + pix];
    }

    float4 acc[Lc];
#pragma unroll
    for (int t = 0; t < Lc; ++t) acc[t] = make_float4(0.f, 0.f, 0.f, 0.f);

    for (int k = 0; k < Lc; ++k) {       // dynamic, wave-uniform
        // re-load k-frame flow from memory (avoids dynamic register indexing)
        const float fxk = cum_flow[(k * 2 + 0) * HWc + pix];
        const float fyk = cum_flow[(k * 2 + 1) * HWc + pix];
        // identity sample for t == k (weight = mask*exp(0) = 1, coords exact)
        const float4 idv = ((const float4*)(imgT + ((size_t)k * HWc + pix) * Cc))[q];
        const float* __restrict__ bk = imgT + (size_t)k * HWc * Cc;

#pragma unroll
        for (int t = 0; t < Lc; ++t) {
            if (t == k) {
                acc[t].x += idv.x; acc[t].y += idv.y;
                acc[t].z += idv.z; acc[t].w += idv.w;
            } else if (t > k) {          // wave-uniform branch (k in SGPR)
                const float wkt = mask[t * Lc + k] *
                                  __expf(-DECAYc * decay[t * Lc + k]);

                float gx = base_x + (fxs[t] - fxk);
                const float gy = base_y + (fys[t] - fyk);

                // gx = mod(gx + 1, 2) - 1 (Python mod semantics)
                float m = gx + 1.0f;
                m -= 2.0f * floorf(m * 0.5f);
                gx = m - 1.0f;

                const float ix = (gx + 1.0f) * (Wc * 0.5f) - 0.5f;
                const float iy = (gy + 1.0f) * (Hc * 0.5f) - 0.5f;

                const float x0f = floorf(ix);
                const float y0f = floorf(iy);
                const float wx = ix - x0f;
                const float wy = iy - y0f;

                const int x0 = (int)x0f;
                const int y0 = (int)y0f;
                const int x0r = x0 & (Wc - 1);
                const int x1r = (x0 + 1) & (Wc - 1);
                const int y0c = min(max(y0, 0), Hc - 1);
                const int y1c = min(max(y0 + 1, 0), Hc - 1);

                const float a00 = wkt * (1.0f - wx) * (1.0f - wy);
                const float a01 = wkt * (1.0f - wx) * wy;
                const float a10 = wkt * wx * (1.0f - wy);
                const float a11 = wkt * wx * wy;

                const float4 v00 = ((const float4*)(bk + (y0c * Wc + x0r) * Cc))[q];
                const float4 v10 = ((const float4*)(bk + (y0c * Wc + x1r) * Cc))[q];
                const float4 v01 = ((const float4*)(bk + (y1c * Wc + x0r) * Cc))[q];
                const float4 v11 = ((const float4*)(bk + (y1c * Wc + x1r) * Cc))[q];

                acc[t].x += a00 * v00.x + a10 * v10.x + a01 * v01.x + a11 * v11.x;
                acc[t].y += a00 * v00.y + a10 * v10.y + a01 * v01.y + a11 * v11.y;
                acc[t].z += a00 * v00.z + a10 * v10.z + a01 * v01.z + a11 * v11.z;
                acc[t].w += a00 * v00.w + a10 * v10.w + a01 * v01.w + a11 * v11.w;
            }
        }
    }

    // Epilogue: out (L,C,H,W); 4 planes per thread, 4-line coalescing/instr.
#pragma unroll
    for (int t = 0; t < Lc; ++t) {
        float* __restrict__ op = out + ((size_t)t * Cc + 4 * q) * HWc + pix;
        op[0 * HWc] = acc[t].x;
        op[1 * HWc] = acc[t].y;
        op[2 * HWc] = acc[t].z;
        op[3 * HWc] = acc[t].w;
    }
}

// ---------------------------------------------------------------------------
// Fallback (Round-1 kernel): used only if ws_size is too small for imgT.
// ---------------------------------------------------------------------------
__global__ __launch_bounds__(256) void gridsample_warp_acc(
    const float* __restrict__ img, const float* __restrict__ cum_flow,
    const float* __restrict__ mask, const float* __restrict__ decay,
    float* __restrict__ out)
{
    const int w = threadIdx.x, h = blockIdx.x, t = blockIdx.y;
    const int pix = h * Wc + w;
    const float base_x = w * (2.0f / Wc) - 1.0f + 1.0f / Wc;
    const float base_y = h * (2.0f / Hc) - 1.0f + 1.0f / Hc;
    const float fxt = cum_flow[(t * 2 + 0) * HWc + pix];
    const float fyt = cum_flow[(t * 2 + 1) * HWc + pix];
    float acc[Cc];
#pragma unroll
    for (int c = 0; c < Cc; ++c) acc[c] = 0.0f;
    for (int k = 0; k <= t; ++k) {
        const float wkt = mask[t * Lc + k] * __expf(-DECAYc * decay[t * Lc + k]);
        const float fxk = cum_flow[(k * 2 + 0) * HWc + pix];
        const float fyk = cum_flow[(k * 2 + 1) * HWc + pix];
        float gx = base_x + (fxt - fxk);
        const float gy = base_y + (fyt - fyk);
        float m = gx + 1.0f;
        m -= 2.0f * floorf(m * 0.5f);
        gx = m - 1.0f;
        const float ix = (gx + 1.0f) * (Wc * 0.5f) - 0.5f;
        const float iy = (gy + 1.0f) * (Hc * 0.5f) - 0.5f;
        const float x0f = floorf(ix), y0f = floorf(iy);
        const float wx = ix - x0f, wy = iy - y0f;
        const int x0 = (int)x0f, y0 = (int)y0f;
        const int x0r = x0 & (Wc - 1), x1r = (x0 + 1) & (Wc - 1);
        const int y0c = min(max(y0, 0), Hc - 1), y1c = min(max(y0 + 1, 0), Hc - 1);
        const float a00 = wkt * (1.0f - wx) * (1.0f - wy);
        const float a01 = wkt * (1.0f - wx) * wy;
        const float a10 = wkt * wx * (1.0f - wy);
        const float a11 = wkt * wx * wy;
        const int o00 = y0c * Wc + x0r, o01 = y1c * Wc + x0r;
        const int o10 = y0c * Wc + x1r, o11 = y1c * Wc + x1r;
        const float* __restrict__ ik = img + (size_t)k * Cc * HWc;
#pragma unroll
        for (int c = 0; c < Cc; ++c) {
            const float* __restrict__ p = ik + c * HWc;
            acc[c] += p[o00] * a00 + p[o01] * a01 + p[o10] * a10 + p[o11] * a11;
        }
    }
    float* __restrict__ op = out + (size_t)t * Cc * HWc + pix;
#pragma unroll
    for (int c = 0; c < Cc; ++c) op[c * HWc] = acc[c];
}

extern "C" void kernel_launch(void* const* d_in, const int* in_sizes, int n_in,
                              void* d_out, int out_size, void* d_ws, size_t ws_size,
                              hipStream_t stream) {
    const float* img      = (const float*)d_in[0];
    const float* cum_flow = (const float*)d_in[1];
    const float* mask     = (const float*)d_in[2];
    const float* decay    = (const float*)d_in[3];
    float* out = (float*)d_out;

    const size_t needed = (size_t)Lc * HWc * Cc * sizeof(float);  // 32 MB
    if (ws_size >= needed) {
        float* imgT = (float*)d_ws;
        dim3 tgrid(HWc / 256, Lc, 1);   // 128 x 16 tiles
        transpose_chlast_lds<<<tgrid, 256, 0, stream>>>(img, imgT);
        gridsample_tmerge<<<512, 256, 0, stream>>>(imgT, cum_flow, mask, decay, out);
    } else {
        dim3 grid(Hc, Lc, 1);
        gridsample_warp_acc<<<grid, Wc, 0, stream>>>(img, cum_flow, mask, decay, out);
    }
}